// Round 1
// baseline (290.107 us; speedup 1.0000x reference)
//
#include <hip/hip_runtime.h>
#include <stdint.h>

typedef unsigned short u16;
typedef __bf16 bf16x8 __attribute__((ext_vector_type(8)));
typedef float f32x4 __attribute__((ext_vector_type(4)));
typedef unsigned short u16x8 __attribute__((ext_vector_type(8)));
typedef unsigned short u16x4 __attribute__((ext_vector_type(4)));

#define B_BATCH 8
#define S_LEN   2048
#define D_DIM   1024
#define U_DIM   1024

// 256x256 tile, BK=64, 8 waves (2M x 4N), 512 threads, 128 KiB LDS dbuf
#define BK 64
#define HALF_U16  16384      // 256*64 u16 (one A or B tile)
#define TILE_U16  32768      // A+B per buffer
#define LDS_U16   65536      // double buffer

__device__ __forceinline__ float bf2f(u16 h) {
    union { unsigned u; float f; } c; c.u = ((unsigned)h) << 16; return c.f;
}
__device__ __forceinline__ u16 f2bf(float f) {
    union { float f; unsigned u; } c; c.f = f;
    unsigned r = c.u + 0x7fffu + ((c.u >> 16) & 1u);
    return (u16)(r >> 16);
}

__device__ __forceinline__ void cp16(u16* lds, const u16* g) {
    __builtin_amdgcn_global_load_lds((__attribute__((address_space(1))) void*)g,
                                     (__attribute__((address_space(3))) void*)lds,
                                     16, 0, 0);
}

// raw barrier: no compiler-inserted vmcnt(0) drain (that drain is the m97
// ceiling); "memory" clobber = code-motion fence for all memory ops.
__device__ __forceinline__ void barrier_raw() { asm volatile("s_barrier" ::: "memory"); }

// stage one 256x64 bf16 tile (16 KiB x ... = 32 KiB): 4 x global_load_lds
// dwordx4 per thread. LDS dest linear (wave-uniform base + lane*16); swizzle
// applied on the GLOBAL source chunk index (both-sides-or-neither, rule #21).
__device__ __forceinline__ void stage4(u16* __restrict__ dst, const u16* __restrict__ src,
                                       int ld, int row0, int kc, int tid) {
    #pragma unroll
    for (int s = 0; s < 4; ++s) {
        const int c = tid + 512 * s;
        const int r = c >> 3;
        const int q = (c & 7) ^ (r & 7);
        cp16(dst + c * 8, src + (long long)(row0 + r) * ld + kc + q * 8);
    }
}

__device__ __forceinline__ void ldsA8(bf16x8* a, const u16* __restrict__ T,
                                      int rbase, int lm, int lq, int sw) {
    #pragma unroll
    for (int i = 0; i < 4; ++i)
        #pragma unroll
        for (int ks = 0; ks < 2; ++ks)
            a[i * 2 + ks] = *(const bf16x8*)(T + (rbase + i * 16 + lm) * BK + (((ks * 4 + lq) ^ sw) * 8));
}
__device__ __forceinline__ void ldsB4(bf16x8* b, const u16* __restrict__ T,
                                      int rbase, int lm, int lq, int sw) {
    #pragma unroll
    for (int j = 0; j < 2; ++j)
        #pragma unroll
        for (int ks = 0; ks < 2; ++ks)
            b[j * 2 + ks] = *(const bf16x8*)(T + (rbase + j * 16 + lm) * BK + (((ks * 4 + lq) ^ sw) * 8));
}

// one phase's MFMA cluster: 16 x mfma_16x16x32_bf16 (quadrant x K=64).
// setprio(1) = T5; sched_barrier(0) pins MFMAs + their lgkm waits BEFORE the
// trailing s_barrier (rule #18: register-only MFMAs otherwise cross barriers).
template<int I0, int J0>
__device__ __forceinline__ void mmaq(f32x4 (*acc)[4], const bf16x8* a, const bf16x8* b) {
    __builtin_amdgcn_s_setprio(1);
    #pragma unroll
    for (int i = 0; i < 4; ++i)
        #pragma unroll
        for (int j = 0; j < 2; ++j)
            #pragma unroll
            for (int ks = 0; ks < 2; ++ks)
                acc[I0 + i][J0 + j] = __builtin_amdgcn_mfma_f32_16x16x32_bf16(
                    a[i * 2 + ks], b[j * 2 + ks], acc[I0 + i][J0 + j], 0, 0, 0);
    __builtin_amdgcn_s_setprio(0);
    __builtin_amdgcn_sched_barrier(0);
}

// 256x256x K GEMM core, 4-phase-per-K-tile schedule:
//   ph0: ds A-half0 (8xb128) + B-half0 (4) | stage next-A | bar | MFMA q00 | bar
//   ph1: ds B-half1 (4)                    | stage next-B | bar | MFMA q01 | bar
//   ph2: ds A-half1 (8)                                   | bar | MFMA q11 | bar
//   ph3: ds B-half0 (4) | vmcnt(0) (loads had 3 phases of cover) | bar | MFMA q10 | bar
// Staging loads issued at ph0/ph1 stay in flight across 5 barriers; the only
// vmcnt wait per K-tile is at ph3, publishing buf^1 for the next tile.
__device__ __forceinline__ void gemm256(
    const u16* __restrict__ A, int lda,
    const u16* __restrict__ Bt, int ldb,
    int m0, int n0, int K,
    u16* lds, int tid, f32x4 (*acc)[4])
{
    const int lane = tid & 63;
    const int wid  = tid >> 6;
    const int wmh  = (wid >> 2) * 128;   // wave row-half: 0 or 128
    const int wnh  = (wid & 3) * 64;     // wave col: 0/64/128/192
    const int lm   = lane & 15;
    const int lq   = lane >> 4;
    const int sw   = lm & 7;

    // prologue: stage tile 0 into buf0
    stage4(lds,            A,  lda, m0, 0, tid);
    stage4(lds + HALF_U16, Bt, ldb, n0, 0, tid);
    asm volatile("s_waitcnt vmcnt(0)" ::: "memory");
    barrier_raw();

    const int NT = K >> 6;
    int buf = 0;
    for (int kt = 0; kt < NT; ++kt) {
        const u16* As  = lds + buf * TILE_U16;
        const u16* Bs  = As + HALF_U16;
        u16* Asn = lds + (buf ^ 1) * TILE_U16;
        u16* Bsn = Asn + HALF_U16;
        const int kn = (kt + 1) << 6;
        const bool pre = (kt + 1) < NT;
        bf16x8 a[8], b[4];

        // ---- phase 0: C(m 0-3, n 0-1)
        ldsA8(a, As, wmh, lm, lq, sw);
        ldsB4(b, Bs, wnh, lm, lq, sw);
        if (pre) stage4(Asn, A, lda, m0, kn, tid);
        barrier_raw();
        mmaq<0, 0>(acc, a, b);
        barrier_raw();

        // ---- phase 1: C(m 0-3, n 2-3)
        ldsB4(b, Bs, wnh + 32, lm, lq, sw);
        if (pre) stage4(Bsn, Bt, ldb, n0, kn, tid);
        barrier_raw();
        mmaq<0, 2>(acc, a, b);
        barrier_raw();

        // ---- phase 2: C(m 4-7, n 2-3)
        ldsA8(a, As, wmh + 64, lm, lq, sw);
        barrier_raw();
        mmaq<4, 2>(acc, a, b);
        barrier_raw();

        // ---- phase 3: C(m 4-7, n 0-1); publish next tile's staging
        ldsB4(b, Bs, wnh, lm, lq, sw);
        if (pre) asm volatile("s_waitcnt vmcnt(0)" ::: "memory");
        barrier_raw();
        mmaq<4, 0>(acc, a, b);
        barrier_raw();

        buf ^= 1;
    }
}

// z-pinned (z = lid&7 -> XCD) + m-fastest swizzle for L2 locality
__device__ __forceinline__ void swizzle_mnz(int ph, int& mi, int& ni, int& z) {
    const int lid = blockIdx.x + gridDim.x * (blockIdx.y + gridDim.y * blockIdx.z);
    z = lid & 7;
    const int t = lid >> 3;
    const int ntn = gridDim.x;
    const int panel = t / (ph * ntn);
    const int r = t - panel * (ph * ntn);
    mi = panel * ph + (r % ph);
    ni = r / ph;
}

// ---------------- kernel 1: prep (x cvt, W transposes, rowsum zero) --------
__global__ __launch_bounds__(256) void prep(
    const float* __restrict__ x, u16* __restrict__ xb,
    const float* __restrict__ Wq, const float* __restrict__ Wk,
    const float* __restrict__ Wv, u16* __restrict__ WT,
    float* __restrict__ rowsum)
{
    __shared__ u16 tile[32][33];
    const int b = blockIdx.x;
    const int tid = threadIdx.x;
    if (b < 16384) {
        const int i = b * 256 + tid;
        float4 v = ((const float4*)x)[i];
        ushort4 o;
        o.x = f2bf(v.x); o.y = f2bf(v.y); o.z = f2bf(v.z); o.w = f2bf(v.w);
        ((ushort4*)xb)[i] = o;
    } else if (b < 16384 + 3072) {
        const int b2 = b - 16384;
        const int w = b2 >> 10;
        const int idx = b2 & 1023;
        const float* src = (w == 0) ? Wq : (w == 1) ? Wk : Wv;
        u16* dst = WT + (size_t)w * D_DIM * U_DIM;
        const int c0 = (idx & 31) * 32, rr0 = (idx >> 5) * 32;
        const int tx = tid & 31, ty = tid >> 5;
        #pragma unroll
        for (int i = 0; i < 32; i += 8)
            tile[ty + i][tx] = f2bf(src[(long long)(rr0 + ty + i) * U_DIM + c0 + tx]);
        __syncthreads();
        #pragma unroll
        for (int i = 0; i < 32; i += 8)
            dst[(long long)(c0 + ty + i) * D_DIM + rr0 + tx] = tile[tx][ty + i];
    } else {
        const int i = (b - 16384 - 3072) * 256 + tid;
        float4 z4; z4.x = z4.y = z4.z = z4.w = 0.0f;
        ((float4*)rowsum)[i] = z4;
    }
}

// ------------- kernel 2: fused QKV projection (V written transposed) -------
// grid (12, 64): tgt = bx>>2, ni = bx&3, mi = by.
__global__ __launch_bounds__(512, 2) void qkv_proj(
    const u16* __restrict__ xb, const u16* __restrict__ WT,
    const float* __restrict__ bq, const float* __restrict__ bk,
    const float* __restrict__ bv,
    u16* __restrict__ Q, u16* __restrict__ Ko, u16* __restrict__ VT)
{
    __shared__ __align__(16) u16 smem[LDS_U16];   // 128 KiB; reused as 256x256 T
    const int tgt = blockIdx.x >> 2;
    const int n0 = (blockIdx.x & 3) * 256;
    const int m0 = blockIdx.y * 256;
    const int tid = threadIdx.x;
    const int lane = tid & 63, wid = tid >> 6;
    const int wmh = (wid >> 2) * 128, wnh = (wid & 3) * 64;
    const int lm = lane & 15, lq = lane >> 4;

    const u16* Bt = WT + (size_t)tgt * (D_DIM * U_DIM);
    const float* bias = (tgt == 0) ? bq : (tgt == 1) ? bk : bv;

    f32x4 acc[8][4] = {};
    gemm256(xb, D_DIM, Bt, D_DIM, m0, n0, D_DIM, smem, tid, acc);

    if (tgt < 2) {
        u16* C = (tgt == 0) ? Q : Ko;
        #pragma unroll
        for (int j = 0; j < 4; ++j) {
            const int n = n0 + wnh + j * 16 + lm;
            const float bvv = bias[n];
            #pragma unroll
            for (int i = 0; i < 8; ++i) {
                const long long mr = m0 + wmh + i * 16 + lq * 4;
                #pragma unroll
                for (int r = 0; r < 4; ++r)
                    C[(mr + r) * U_DIM + n] = f2bf(acc[i][j][r] + bvv);
            }
        }
    } else {
        // V: transpose 256x256 tile through LDS, write VT[u][s] coalesced.
        // T elem (row m-local, col n-local) at u16 idx:
        //   col*256 + ((row>>3)^(col&31))*8 + (row&7)   (XOR bank swizzle)
        __syncthreads();   // all waves done with K-loop LDS
        #pragma unroll
        for (int j = 0; j < 4; ++j) {
            const int cl = wnh + j * 16 + lm;
            const float bvv = bias[n0 + cl];
            #pragma unroll
            for (int i = 0; i < 8; ++i) {
                const int rowb = wmh + i * 16 + lq * 4;   // 4 rows, same 8-block
                u16x4 pk;
                #pragma unroll
                for (int r = 0; r < 4; ++r) pk[r] = f2bf(acc[i][j][r] + bvv);
                const int idx = cl * 256 + (((rowb >> 3) ^ (cl & 31)) * 8) + (rowb & 7);
                *(u16x4*)(smem + idx) = pk;
            }
        }
        __syncthreads();
        const int zb = m0 >> 11;            // batch
        const int s0 = m0 & 2047;           // seq offset within batch
        u16* VTg = VT + (size_t)zb * ((size_t)S_LEN * U_DIM);
        #pragma unroll
        for (int s = 0; s < 16; ++s) {
            const int cid = tid + 512 * s;   // 8192 chunks: col(256) x m8(32)
            const int cl = cid >> 5;
            const int m8 = cid & 31;
            u16x8 v = *(const u16x8*)(smem + cl * 256 + ((m8 ^ (cl & 31)) * 8));
            *(u16x8*)(VTg + (size_t)(n0 + cl) * S_LEN + s0 + m8 * 8) = v;
        }
    }
}

// ------ kernel 3: scores + exp + mask + rowsum (softmax w/o max-sub) -------
__global__ __launch_bounds__(512, 2) void scores_exp(
    const u16* __restrict__ Qb, const u16* __restrict__ Kb,
    u16* __restrict__ E, const int* __restrict__ mask,
    float* __restrict__ rowsum, int ph)
{
    __shared__ __align__(16) u16 smem[LDS_U16];

    int mi, ni, z;
    swizzle_mnz(ph, mi, ni, z);
    const int m0 = mi * 256, n0 = ni * 256;
    const long long SU = (long long)S_LEN * U_DIM;
    const long long SS = (long long)S_LEN * S_LEN;

    const int tid = threadIdx.x;
    const int lane = tid & 63, wid = tid >> 6;
    const int wmh = (wid >> 2) * 128, wnh = (wid & 3) * 64;
    const int lm = lane & 15, lq = lane >> 4;

    f32x4 acc[8][4] = {};
    gemm256(Qb + (long long)z * SU, U_DIM, Kb + (long long)z * SU, U_DIM,
            m0, n0, U_DIM, smem, tid, acc);

    u16* Eg = E + (long long)z * SS;
    const int* mrow = mask + (size_t)z * S_LEN;

    int mj[4];
    #pragma unroll
    for (int j = 0; j < 4; ++j) mj[j] = mrow[n0 + wnh + j * 16 + lm];

    #pragma unroll
    for (int i = 0; i < 8; ++i) {
        #pragma unroll
        for (int r = 0; r < 4; ++r) {
            const int row = m0 + wmh + i * 16 + lq * 4 + r;
            const int mi_ = mrow[row];
            float partial = 0.0f;
            #pragma unroll
            for (int j = 0; j < 4; ++j) {
                // m_i=0 row: uniform -1e4 shift cancels in softmax -> bias 0.
                // m_i=1 & m_j=0: exactly 0 (ref: exp(-1e4-..) == 0 in fp32).
                float e = (mi_ && !mj[j]) ? 0.0f : __expf(acc[i][j][r] * 0.03125f);
                const u16 h = f2bf(e);
                Eg[(long long)row * S_LEN + n0 + wnh + j * 16 + lm] = h;
                partial += bf2f(h);   // sum what PV will actually read
            }
            partial += __shfl_xor(partial, 1, 64);
            partial += __shfl_xor(partial, 2, 64);
            partial += __shfl_xor(partial, 4, 64);
            partial += __shfl_xor(partial, 8, 64);
            if (lm == 0)
                atomicAdd(&rowsum[(size_t)z * S_LEN + row], partial);
        }
    }
}

// --------------- kernel 4: out = (E @ V) / rowsum, fp32 out ----------------
__global__ __launch_bounds__(512, 2) void pv_gemm(
    const u16* __restrict__ E, const u16* __restrict__ VT,
    float* __restrict__ out, const float* __restrict__ rowsum, int ph)
{
    __shared__ __align__(16) u16 smem[LDS_U16];

    int mi, ni, z;
    swizzle_mnz(ph, mi, ni, z);
    const int m0 = mi * 256, n0 = ni * 256;
    const long long SU = (long long)S_LEN * U_DIM;
    const long long SS = (long long)S_LEN * S_LEN;

    const int tid = threadIdx.x;
    const int lane = tid & 63, wid = tid >> 6;
    const int wmh = (wid >> 2) * 128, wnh = (wid & 3) * 64;
    const int lm = lane & 15, lq = lane >> 4;

    f32x4 acc[8][4] = {};
    gemm256(E + (long long)z * SS, S_LEN, VT + (long long)z * SU, S_LEN,
            m0, n0, S_LEN, smem, tid, acc);

    float* Cg = out + (long long)z * SU;
    const float* rs = rowsum + (size_t)z * S_LEN;

    #pragma unroll
    for (int i = 0; i < 8; ++i) {
        #pragma unroll
        for (int r = 0; r < 4; ++r) {
            const int row = m0 + wmh + i * 16 + lq * 4 + r;
            const float inv = 1.0f / rs[row];
            #pragma unroll
            for (int j = 0; j < 4; ++j)
                Cg[(long long)row * U_DIM + n0 + wnh + j * 16 + lm] = acc[i][j][r] * inv;
        }
    }
}

extern "C" void kernel_launch(void* const* d_in, const int* in_sizes, int n_in,
                              void* d_out, int out_size, void* d_ws, size_t ws_size,
                              hipStream_t stream)
{
    (void)in_sizes; (void)n_in; (void)out_size; (void)ws_size;
    const float* x    = (const float*)d_in[0];
    const int*   mask = (const int*)d_in[1];
    const float* Wq   = (const float*)d_in[2];
    const float* bq   = (const float*)d_in[3];
    const float* Wk   = (const float*)d_in[4];
    const float* bk   = (const float*)d_in[5];
    const float* Wv   = (const float*)d_in[6];
    const float* bv   = (const float*)d_in[7];

    const size_t DU  = (size_t)D_DIM * U_DIM;
    const size_t BSU = (size_t)B_BATCH * S_LEN * U_DIM;

    // ws layout (u16 units): Qb | Kb | VTb | WT(x3) | rowsum | E (aliases xb)
    u16* ws  = (u16*)d_ws;
    u16* Qb  = ws;
    u16* Kb  = Qb + BSU;
    u16* VTb = Kb + BSU;
    u16* WT  = VTb + BSU;
    float* rowsum = (float*)(WT + 3 * DU);
    u16* E   = (u16*)(rowsum + (size_t)B_BATCH * S_LEN);
    u16* xb  = E;   // alias: xb dead before E is written

    // 1) prep: x cvt (16384 blocks) + 3 W transposes (3072) + rowsum zero (16)
    prep<<<dim3(16384 + 3072 + 16), dim3(256), 0, stream>>>(x, xb, Wq, Wk, Wv, WT, rowsum);

    // 2) fused QKV projections; V lands pre-transposed. 256^2 tiles.
    qkv_proj<<<dim3(12, 64), dim3(512), 0, stream>>>(xb, WT, bq, bk, bv, Qb, Kb, VTb);

    // 3) E = exp(QK^T/32) masked, + rowsum atomics (z-pinned, 8x8 tiles/batch)
    scores_exp<<<dim3(8, 8, 8), dim3(512), 0, stream>>>(Qb, Kb, E, mask, rowsum, 8);

    // 4) out = (E V) / rowsum (z-pinned, m fastest for VT L2 residency)
    pv_gemm<<<dim3(4, 8, 8), dim3(512), 0, stream>>>(E, VTb, (float*)d_out, rowsum, 8);
}